// Round 1
// baseline (852.350 us; speedup 1.0000x reference)
//
#include <hip/hip_runtime.h>
#include <hip/hip_bf16.h>
#include <stdint.h>

// Problem constants (from reference)
#define E_EDGES 1048576
#define NN 50000
#define NODE_H 128
#define EDGE_H 64
#define GNN_H 128
#define K1 320  // 2*NODE_H + EDGE_H
#define K2 256  // NODE_H + GNN_H

typedef __bf16 bf16_t;
typedef __bf16 bf16x8 __attribute__((ext_vector_type(8)));
typedef float floatx4 __attribute__((ext_vector_type(4)));

// Workspace layout (bytes)
#define OFF_FLAG 0
#define OFF_CNT 256
#define CNT_BYTES (NN * 4)                 // 200000
#define OFF_W1T 200448                     // 256 + 200000 rounded up to 256
#define W1T_BYTES (K1 * GNN_H * 2)         // 81920
#define OFF_W2T (OFF_W1T + W1T_BYTES)      // 282368
#define W2T_BYTES (K2 * GNN_H * 2)         // 65536
#define OFF_S (OFF_W2T + W2T_BYTES)        // 347904
#define S_BYTES (NN * GNN_H * 4)           // 25600000
#define WS_NEED (OFF_S + (size_t)S_BYTES)

__device__ __forceinline__ long load_idx(const void* ei, int is64, long off) {
    return is64 ? (long)((const long long*)ei)[off] : (long)((const int*)ei)[off];
}

// Prep: transpose W1,W2 to bf16 [N][K]; detect edge_index dtype (int64 high words all zero).
__global__ void prep_kernel(const float* __restrict__ W1, const float* __restrict__ W2,
                            const int* __restrict__ ei32, char* __restrict__ ws) {
    bf16_t* w1t = (bf16_t*)(ws + OFF_W1T);
    bf16_t* w2t = (bf16_t*)(ws + OFF_W2T);
    int tid = blockIdx.x * blockDim.x + threadIdx.x;
    int nt = gridDim.x * blockDim.x;
    for (int i = tid; i < K1 * GNN_H; i += nt) {
        int n = i / K1, k = i - n * K1;
        w1t[i] = (bf16_t)W1[k * GNN_H + n];
    }
    for (int i = tid; i < K2 * GNN_H; i += nt) {
        int n = i / K2, k = i - n * K2;
        w2t[i] = (bf16_t)W2[k * GNN_H + n];
    }
    if (blockIdx.x == 0) {
        __shared__ int any_nonzero;
        if (threadIdx.x == 0) any_nonzero = 0;
        __syncthreads();
        // If data is int64 (values < 50000), every odd int32 slot is 0.
        if (ei32[2 * threadIdx.x + 1] != 0) atomicOr(&any_nonzero, 1);
        __syncthreads();
        if (threadIdx.x == 0) *(int*)(ws + OFF_FLAG) = (any_nonzero == 0) ? 1 : 0;
    }
}

__global__ void count_kernel(const void* __restrict__ ei, const char* __restrict__ ws,
                             float* __restrict__ cnt) {
    int is64 = *(const int*)(ws + OFF_FLAG);
    int e = blockIdx.x * blockDim.x + threadIdx.x;
    if (e < E_EDGES) {
        long c = load_idx(ei, is64, (long)E_EDGES + e);
        atomicAdd(cnt + c, 1.0f);
    }
}

// Edge MLP + scatter-add. Block = 4 waves; wave w owns N-range [w*32, w*32+32).
// Per tile: 16 edges. A-frags gathered from x/edge_attr directly (f32->bf16 in regs).
__global__ __launch_bounds__(256) void edge_kernel(
    const float* __restrict__ x, const void* __restrict__ ei,
    const float* __restrict__ ea, const float* __restrict__ b1,
    const char* __restrict__ ws, float* __restrict__ s) {
    const bf16_t* w1t = (const bf16_t*)(ws + OFF_W1T);
    int is64 = *(const int*)(ws + OFF_FLAG);
    int lane = threadIdx.x & 63;
    int w = threadIdx.x >> 6;
    int li = lane & 15;  // B col / A row selector
    int h = lane >> 4;   // k-chunk selector
    int n0 = w * 32;

    // B fragments in registers: 2 n-subtiles x 10 k-steps (80 VGPRs)
    bf16x8 bf[2][10];
#pragma unroll
    for (int t = 0; t < 2; ++t)
#pragma unroll
        for (int ks = 0; ks < 10; ++ks)
            bf[t][ks] = *(const bf16x8*)(w1t + (long)(n0 + t * 16 + li) * K1 + ks * 32 + h * 8);
    float bias0 = b1[n0 + li];
    float bias1 = b1[n0 + 16 + li];

    const int ntiles = E_EDGES / 16;
    for (int tile = blockIdx.x; tile < ntiles; tile += gridDim.x) {
        int m0 = tile * 16;
        int e = m0 + li;
        long rowi = load_idx(ei, is64, e);
        long coli = load_idx(ei, is64, (long)E_EDGES + e);
        const float* pr = x + rowi * NODE_H + h * 8;
        const float* pc = x + coli * NODE_H + h * 8;
        const float* pe = ea + (long)e * EDGE_H + h * 8;
        floatx4 acc0 = {0.f, 0.f, 0.f, 0.f};
        floatx4 acc1 = {0.f, 0.f, 0.f, 0.f};
#pragma unroll
        for (int ks = 0; ks < 10; ++ks) {
            // k-chunk [32*ks, 32*ks+32): ks 0-3 -> x[row], 4-7 -> x[col], 8-9 -> edge_attr
            const float* src = (ks < 4) ? (pr + ks * 32) : (ks < 8) ? (pc + (ks - 4) * 32)
                                                                    : (pe + (ks - 8) * 32);
            floatx4 f0 = *(const floatx4*)(src);
            floatx4 f1 = *(const floatx4*)(src + 4);
            bf16x8 a;
#pragma unroll
            for (int j = 0; j < 4; ++j) {
                a[j] = (bf16_t)f0[j];
                a[j + 4] = (bf16_t)f1[j];
            }
            acc0 = __builtin_amdgcn_mfma_f32_16x16x32_bf16(a, bf[0][ks], acc0, 0, 0, 0);
            acc1 = __builtin_amdgcn_mfma_f32_16x16x32_bf16(a, bf[1][ks], acc1, 0, 0, 0);
        }
        // Epilogue: C row = edge m0+4*h+r, col = n0 + t*16 + li. relu then scatter.
        long cols[4];
#pragma unroll
        for (int r = 0; r < 4; ++r)
            cols[r] = load_idx(ei, is64, (long)E_EDGES + m0 + h * 4 + r);
#pragma unroll
        for (int r = 0; r < 4; ++r) {
            float v0 = fmaxf(acc0[r] + bias0, 0.f);
            float v1 = fmaxf(acc1[r] + bias1, 0.f);
            atomicAdd(s + cols[r] * GNN_H + n0 + li, v0);
            atomicAdd(s + cols[r] * GNN_H + n0 + 16 + li, v1);
        }
    }
}

// Node MLP: out = relu([x, s/cnt] @ W2 + b2). 16 nodes per block, 4 waves over N.
__global__ __launch_bounds__(256) void node_kernel(
    const float* __restrict__ x, const float* __restrict__ b2,
    const char* __restrict__ ws, const float* __restrict__ s,
    float* __restrict__ out) {
    const bf16_t* w2t = (const bf16_t*)(ws + OFF_W2T);
    const float* cnt = (const float*)(ws + OFF_CNT);
    int lane = threadIdx.x & 63;
    int w = threadIdx.x >> 6;
    int li = lane & 15;
    int h = lane >> 4;
    int n0 = w * 32;

    bf16x8 bf[2][8];
#pragma unroll
    for (int t = 0; t < 2; ++t)
#pragma unroll
        for (int ks = 0; ks < 8; ++ks)
            bf[t][ks] = *(const bf16x8*)(w2t + (long)(n0 + t * 16 + li) * K2 + ks * 32 + h * 8);
    float bias0 = b2[n0 + li];
    float bias1 = b2[n0 + 16 + li];

    int m0 = blockIdx.x * 16;
    int i = m0 + li;
    float rc = 1.0f / fmaxf(cnt[i], 1.0f);
    const float* px = x + (long)i * NODE_H + h * 8;
    const float* ps = s + (long)i * GNN_H + h * 8;
    floatx4 acc0 = {0.f, 0.f, 0.f, 0.f};
    floatx4 acc1 = {0.f, 0.f, 0.f, 0.f};
#pragma unroll
    for (int ks = 0; ks < 8; ++ks) {
        const float* src = (ks < 4) ? (px + ks * 32) : (ps + (ks - 4) * 32);
        floatx4 f0 = *(const floatx4*)(src);
        floatx4 f1 = *(const floatx4*)(src + 4);
        if (ks >= 4) {
            f0 *= rc;
            f1 *= rc;
        }
        bf16x8 a;
#pragma unroll
        for (int j = 0; j < 4; ++j) {
            a[j] = (bf16_t)f0[j];
            a[j + 4] = (bf16_t)f1[j];
        }
        acc0 = __builtin_amdgcn_mfma_f32_16x16x32_bf16(a, bf[0][ks], acc0, 0, 0, 0);
        acc1 = __builtin_amdgcn_mfma_f32_16x16x32_bf16(a, bf[1][ks], acc1, 0, 0, 0);
    }
    __syncthreads();  // allow s == out (in-place fallback): all reads of s done before stores
#pragma unroll
    for (int r = 0; r < 4; ++r) {
        long ir = m0 + h * 4 + r;
        out[ir * GNN_H + n0 + li] = fmaxf(acc0[r] + bias0, 0.f);
        out[ir * GNN_H + n0 + 16 + li] = fmaxf(acc1[r] + bias1, 0.f);
    }
}

extern "C" void kernel_launch(void* const* d_in, const int* in_sizes, int n_in,
                              void* d_out, int out_size, void* d_ws, size_t ws_size,
                              hipStream_t stream) {
    const float* x = (const float*)d_in[0];
    const void* ei = d_in[1];
    const float* ea = (const float*)d_in[2];
    const float* W1 = (const float*)d_in[3];
    const float* b1 = (const float*)d_in[4];
    const float* W2 = (const float*)d_in[5];
    const float* b2 = (const float*)d_in[6];
    float* out = (float*)d_out;
    char* ws = (char*)d_ws;

    float* cnt = (float*)(ws + OFF_CNT);
    float* s = (ws_size >= WS_NEED) ? (float*)(ws + OFF_S) : out;

    hipMemsetAsync(cnt, 0, CNT_BYTES, stream);
    hipMemsetAsync(s, 0, S_BYTES, stream);
    prep_kernel<<<32, 256, 0, stream>>>(W1, W2, (const int*)ei, ws);
    count_kernel<<<E_EDGES / 256, 256, 0, stream>>>(ei, ws, cnt);
    edge_kernel<<<4096, 256, 0, stream>>>(x, ei, ea, b1, ws, s);
    node_kernel<<<NN / 16, 256, 0, stream>>>(x, b2, ws, s, out);
}